// Round 6
// baseline (268.037 us; speedup 1.0000x reference)
//
#include <hip/hip_runtime.h>
#include <hip/hip_bf16.h>

#define Bsz  4096
#define Tn   256
#define CIN  16
#define NCLS 10
#define MBR  8           // real batch rows per rec block (tile is 16, rows 8-15 garbage)
#define SH   72          // comb row stride in shorts (144B: 16B-aligned, ~2-way banks)

typedef __attribute__((ext_vector_type(8))) short short8;
typedef __attribute__((ext_vector_type(4))) float f32x4;

#if __has_builtin(__builtin_amdgcn_exp2f)
#define EXP2F(x) __builtin_amdgcn_exp2f(x)
#else
#define EXP2F(x) exp2f(x)
#endif
#define RCPF(x) __builtin_amdgcn_rcpf(x)

#define LOG2E 1.442695041f

__device__ inline ushort f2bf(float f) {
    union { float f; unsigned u; } x; x.f = f;
    return (ushort)((x.u + 0x7FFF + ((x.u >> 16) & 1)) >> 16);  // RNE
}

// ================= Kernel A: recurrence =====================================
// 4 waves/block, wave ub owns gate units 16ub..16ub+15 (all 4 gates).
// MB=8 real rows -> grid 512 -> 2 independent blocks/CU (stall hiding).
// x bypasses LDS: xz[g] = Wx_g x_t + bias via MFMA, pipelined on global loads.
// comb holds h only. Head logits (11 cols) streamed to ws [B][T][12] f32.
__global__ __launch_bounds__(256, 2) void rec_kernel(
    const float* __restrict__ x,  const float* __restrict__ Wl, const float* __restrict__ bl,
    const float* __restrict__ Wc, const float* __restrict__ bc,
    const float* __restrict__ Wd, const float* __restrict__ bd,
    float* __restrict__ wslog)
{
    __shared__ alignas(16) ushort comb[2][16][SH];   // h_{t} double-buffered, bf16
    const int tid  = threadIdx.x;
    const int ub   = tid >> 6;       // wave id = unit block
    const int lane = tid & 63;
    const int col  = lane & 15;
    const int grp  = lane >> 4;
    const int b0   = blockIdx.x * MBR;

    for (int i = tid; i < 2 * 16 * SH; i += 256) ((ushort*)comb)[i] = 0;

    // gate weights, exp2-scale folded: i,f,o -> -log2e; g -> +2*log2e
    short8 wh[4][2]; short8 wx[4]; f32x4 biasv[4];
#pragma unroll
    for (int g = 0; g < 4; ++g) {
        const float sc = (g == 3) ? 2.f * LOG2E : -LOG2E;
        const int R = g * 64 + ub * 16 + col;
        const float bv = bl[R] * sc;
        biasv[g] = (f32x4){bv, bv, bv, bv};
#pragma unroll
        for (int kt = 0; kt < 2; ++kt)
#pragma unroll
            for (int i = 0; i < 8; ++i)
                wh[g][kt][i] = (short)f2bf(Wl[R * 80 + 16 + kt * 32 + grp * 8 + i] * sc);
#pragma unroll
        for (int i = 0; i < 8; ++i)
            wx[g][i] = (grp < 2) ? (short)f2bf(Wl[R * 80 + grp * 8 + i] * sc) : (short)0;
    }
    // head weights, natural scale
    short8 wcd[2];
#pragma unroll
    for (int kt = 0; kt < 2; ++kt)
#pragma unroll
        for (int i = 0; i < 8; ++i) {
            const int k = kt * 32 + grp * 8 + i;
            float v = 0.f;
            if (col < 10)       v = Wc[col * 64 + k];
            else if (col == 10) v = Wd[k];
            wcd[kt][i] = (short)f2bf(v);
        }
    const float bv2 = (col < 10) ? bc[col] : ((col == 10) ? bd[0] : 0.f);
    const f32x4 bcdv = {bv2, bv2, bv2, bv2};

    // ---- x pipeline (A-frag rows = col; only grp<2 carry k<16) ----
    const int xrow = min(b0 + col, Bsz - 1);          // cols 8-15: garbage rows
    const float* xbase = x + (size_t)xrow * Tn * CIN + grp * 8;
    float4 xfA = {0, 0, 0, 0}, xfB = {0, 0, 0, 0};    // floats of x_{t+1}
    short8 xcur = {0, 0, 0, 0, 0, 0, 0, 0};
    if (grp < 2) {
        const float4 a = *(const float4*)(xbase);
        const float4 b = *(const float4*)(xbase + 4);
        xcur[0] = (short)f2bf(a.x); xcur[1] = (short)f2bf(a.y);
        xcur[2] = (short)f2bf(a.z); xcur[3] = (short)f2bf(a.w);
        xcur[4] = (short)f2bf(b.x); xcur[5] = (short)f2bf(b.y);
        xcur[6] = (short)f2bf(b.z); xcur[7] = (short)f2bf(b.w);
        xfA = *(const float4*)(xbase + CIN);
        xfB = *(const float4*)(xbase + CIN + 4);
    }
    f32x4 xz[4];
#pragma unroll
    for (int g = 0; g < 4; ++g)
        xz[g] = __builtin_amdgcn_mfma_f32_16x16x32_bf16(xcur, wx[g], biasv[g], 0, 0, 0);
    const float* xp = xbase + 2 * CIN;                // x_{t+2} onward

    float cst[4] = {0, 0, 0, 0};
    const int orow = grp * 4 + ub;                    // head output row (valid if <8)
    float* lgp = wslog + ((size_t)(b0 + orow) * Tn) * 12 + col;

    __syncthreads();   // comb zero-fill visible

    for (int t = 0; t < Tn; ++t) {
        const ushort (*rdb)[SH] = comb[t & 1];
        ushort (*wrb)[SH] = comb[(t + 1) & 1];
        // issue x_{t+2} loads (used next iter)
        float4 nxA = {0, 0, 0, 0}, nxB = {0, 0, 0, 0};
        if (t + 2 < Tn && grp < 2) {
            nxA = *(const float4*)(xp);
            nxB = *(const float4*)(xp + 4);
        }
        xp += CIN;
        // h_{t-1} fragments (k-tiles over 64 units)
        const short8 hb0 = *(const short8*)&rdb[col][grp * 8];
        const short8 hb1 = *(const short8*)&rdb[col][32 + grp * 8];
        // gates: acc = Wx x_t + bias (xz) + Wh h_{t-1}
        f32x4 acc[4];
#pragma unroll
        for (int g = 0; g < 4; ++g) {
            f32x4 z = __builtin_amdgcn_mfma_f32_16x16x32_bf16(hb0, wh[g][0], xz[g], 0, 0, 0);
            acc[g] = __builtin_amdgcn_mfma_f32_16x16x32_bf16(hb1, wh[g][1], z, 0, 0, 0);
        }
        // head logits on h_{t-1}
        f32x4 cz = __builtin_amdgcn_mfma_f32_16x16x32_bf16(hb0, wcd[0], bcdv, 0, 0, 0);
        cz = __builtin_amdgcn_mfma_f32_16x16x32_bf16(hb1, wcd[1], cz, 0, 0, 0);
        // xz for t+1 from x_{t+1} floats (loaded last iter)
        short8 xfr = {0, 0, 0, 0, 0, 0, 0, 0};
        if (grp < 2) {
            xfr[0] = (short)f2bf(xfA.x); xfr[1] = (short)f2bf(xfA.y);
            xfr[2] = (short)f2bf(xfA.z); xfr[3] = (short)f2bf(xfA.w);
            xfr[4] = (short)f2bf(xfB.x); xfr[5] = (short)f2bf(xfB.y);
            xfr[6] = (short)f2bf(xfB.z); xfr[7] = (short)f2bf(xfB.w);
        }
#pragma unroll
        for (int g = 0; g < 4; ++g)
            xz[g] = __builtin_amdgcn_mfma_f32_16x16x32_bf16(xfr, wx[g], biasv[g], 0, 0, 0);
        xfA = nxA; xfB = nxB;
        // cell update + h write
        const int hc = ub * 16 + col;
#pragma unroll
        for (int j = 0; j < 4; ++j) {
            const float ei = EXP2F(acc[0][j]);
            const float ef = EXP2F(acc[1][j]);
            const float eo = EXP2F(acc[2][j]);
            const float eg = EXP2F(acc[3][j]);
            const float A  = 1.f + ei, Bv = 1.f + ef;
            const float G1 = eg + 1.f, G2 = eg - 1.f, O = 1.f + eo;
            const float t0  = A * G1;
            const float num = cst[j] * t0 + G2 * Bv;
            const float den = Bv * t0;
            const float cn  = num * RCPF(den);
            cst[j] = cn;
            const float e2 = EXP2F(2.f * LOG2E * cn);
            const float h  = (e2 - 1.f) * RCPF((e2 + 1.f) * O);
            wrb[grp * 4 + j][hc] = f2bf(h);
        }
        // head store for step t-1 (rows 0..7 only)
        if (t > 0) {
            if (grp < 2 && col < 11) {
                const float v = (ub == 0) ? cz[0] : (ub == 1) ? cz[1]
                              : (ub == 2) ? cz[2] : cz[3];
                lgp[0] = v;
            }
            lgp += 12;
        }
        __syncthreads();
    }
    // epilogue: logits for step Tn-1 from h_{Tn-1}
    {
        const ushort (*rdb)[SH] = comb[Tn & 1];
        const short8 hb0 = *(const short8*)&rdb[col][grp * 8];
        const short8 hb1 = *(const short8*)&rdb[col][32 + grp * 8];
        f32x4 cz = __builtin_amdgcn_mfma_f32_16x16x32_bf16(hb0, wcd[0], bcdv, 0, 0, 0);
        cz = __builtin_amdgcn_mfma_f32_16x16x32_bf16(hb1, wcd[1], cz, 0, 0, 0);
        if (grp < 2 && col < 11) {
            const float v = (ub == 0) ? cz[0] : (ub == 1) ? cz[1]
                          : (ub == 2) ? cz[2] : cz[3];
            lgp[0] = v;
        }
    }
}

// ================= Kernel B: streaming softmax / dec ========================
__global__ __launch_bounds__(256) void head_kernel(
    const float* __restrict__ wslog, float* __restrict__ out, float* __restrict__ dec)
{
    const size_t r = (size_t)blockIdx.x * 256 + threadIdx.x;   // (b,t) row
    const float4* lg = (const float4*)(wslog + r * 12);
    const float4 v0 = lg[0], v1 = lg[1], v2 = lg[2];
    const float e0 = EXP2F(v0.x * LOG2E), e1 = EXP2F(v0.y * LOG2E);
    const float e2 = EXP2F(v0.z * LOG2E), e3 = EXP2F(v0.w * LOG2E);
    const float e4 = EXP2F(v1.x * LOG2E), e5 = EXP2F(v1.y * LOG2E);
    const float e6 = EXP2F(v1.z * LOG2E), e7 = EXP2F(v1.w * LOG2E);
    const float e8 = EXP2F(v2.x * LOG2E), e9 = EXP2F(v2.y * LOG2E);
    const float s = ((e0 + e1) + (e2 + e3)) + ((e4 + e5) + (e6 + e7)) + (e8 + e9);
    const float lse = __logf(s);
    float* lp = out + r * 10;
    ((float2*)lp)[0] = (float2){v0.x - lse, v0.y - lse};
    ((float2*)lp)[1] = (float2){v0.z - lse, v0.w - lse};
    ((float2*)lp)[2] = (float2){v1.x - lse, v1.y - lse};
    ((float2*)lp)[3] = (float2){v1.z - lse, v1.w - lse};
    ((float2*)lp)[4] = (float2){v2.x - lse, v2.y - lse};
    dec[r] = RCPF(1.f + EXP2F(-v2.z * LOG2E));
}

// ================= Kernel C: pnd scan ======================================
__global__ __launch_bounds__(64) void pnd_kernel(
    const float* __restrict__ dec, float* __restrict__ pt)
{
    __shared__ float tile[64][65];
    const int ln = threadIdx.x;
    const int b0 = blockIdx.x * 64;
    float pnd = 1.f;
    for (int tc = 0; tc < Tn; tc += 64) {
#pragma unroll 8
        for (int i = 0; i < 64; ++i)
            tile[i][ln] = dec[(size_t)(b0 + i) * Tn + tc + ln];
        __syncthreads();
        for (int tl = 0; tl < 64; ++tl) {
            const float d = tile[ln][tl];
            float v = d * pnd;
            if (tc + tl == Tn - 1) v = pnd;
            tile[ln][tl] = v;
            pnd *= (1.f - d);
        }
        __syncthreads();
        float* dst = pt + (size_t)(b0 + ln) * Tn + tc;
#pragma unroll 8
        for (int k = 0; k < 64; ++k) dst[k] = tile[ln][k];
        __syncthreads();
    }
}

// ================= Fallback: fused kernel (ws too small) ====================
__global__ __launch_bounds__(512, 2) void dualrnn_fused(
    const float* __restrict__ x,  const float* __restrict__ Wl, const float* __restrict__ bl,
    const float* __restrict__ Wc, const float* __restrict__ bc,
    const float* __restrict__ Wd, const float* __restrict__ bd,
    float* __restrict__ out)
{
    __shared__ alignas(16) ushort comb[2][16][104];
    const int tid  = threadIdx.x;
    const int wave = tid >> 6;
    const int lane = tid & 63;
    const int col  = lane & 15;
    const int grp  = lane >> 4;
    const int b0   = blockIdx.x * 16;
    const bool gatew = (wave < 4);

    for (int i = tid; i < 2 * 16 * 104; i += 512) ((ushort*)comb)[i] = 0;

    short8 wf[4][3]; f32x4 biasv[4];
    short8 wcd[2];   f32x4 bcdv;
    if (gatew) {
#pragma unroll
        for (int g = 0; g < 4; ++g) {
            const float sc = (g == 3) ? 2.f * LOG2E : -LOG2E;
            const int R = g * 64 + wave * 16 + col;
            const float bv = bl[R] * sc;
            biasv[g] = (f32x4){bv, bv, bv, bv};
#pragma unroll
            for (int kt = 0; kt < 3; ++kt)
#pragma unroll
                for (int i = 0; i < 8; ++i) {
                    const int k = kt * 32 + grp * 8 + i;
                    wf[g][kt][i] = (short)f2bf(k < 80 ? Wl[R * 80 + k] * sc : 0.f);
                }
        }
    } else {
#pragma unroll
        for (int kt = 0; kt < 2; ++kt)
#pragma unroll
            for (int i = 0; i < 8; ++i) {
                const int k = kt * 32 + grp * 8 + i;
                float v = 0.f;
                if (col < 10)       v = Wc[col * 64 + k];
                else if (col == 10) v = Wd[k] * -LOG2E;
                wcd[kt][i] = (short)f2bf(v);
            }
        const float bv = (col < 10) ? bc[col] : ((col == 10) ? bd[0] * -LOG2E : 0.f);
        bcdv = (f32x4){bv, bv, bv, bv};
    }
    __syncthreads();
    if (tid < 256) {
        const int r = tid >> 4, ch = tid & 15;
        comb[0][r][ch] = f2bf(x[((size_t)(b0 + r) * Tn) * CIN + ch]);
    }
    __syncthreads();

    float cst[4] = {0, 0, 0, 0};
    float pnd = 1.f;
    const int hw  = wave & 3;
    const int row = grp * 4 + hw;
    float* lp_p = out + ((size_t)(b0 + row) * Tn) * NCLS + col;
    float* pt_p = out + (size_t)Bsz * Tn * NCLS + (size_t)(b0 + row) * Tn;
    const int t2 = hw * 64 + lane;
    const int xr = t2 >> 4, xc = t2 & 15;
    float xva = 0.f;
    const float* xp = x + ((size_t)(b0 + xr) * Tn + 2) * CIN + xc;
    if (!gatew) xva = x[((size_t)(b0 + xr) * Tn + 1) * CIN + xc];

    for (int t = 0; t < Tn; ++t) {
        const ushort (*rdb)[104] = comb[t & 1];
        ushort (*wrb)[104] = comb[(t + 1) & 1];
        if (gatew) {
            const short8 a0 = *(const short8*)&rdb[col][ 0 + grp * 8];
            const short8 a1 = *(const short8*)&rdb[col][32 + grp * 8];
            const short8 a2 = *(const short8*)&rdb[col][64 + grp * 8];
            f32x4 acc[4];
#pragma unroll
            for (int g = 0; g < 4; ++g) {
                f32x4 z = biasv[g];
                z = __builtin_amdgcn_mfma_f32_16x16x32_bf16(a0, wf[g][0], z, 0, 0, 0);
                z = __builtin_amdgcn_mfma_f32_16x16x32_bf16(a1, wf[g][1], z, 0, 0, 0);
                z = __builtin_amdgcn_mfma_f32_16x16x32_bf16(a2, wf[g][2], z, 0, 0, 0);
                acc[g] = z;
            }
            const int hc = 16 + wave * 16 + col;
#pragma unroll
            for (int j = 0; j < 4; ++j) {
                const float ei = EXP2F(acc[0][j]);
                const float ef = EXP2F(acc[1][j]);
                const float eo = EXP2F(acc[2][j]);
                const float eg = EXP2F(acc[3][j]);
                const float A  = 1.f + ei, Bv = 1.f + ef;
                const float G1 = eg + 1.f, G2 = eg - 1.f, O = 1.f + eo;
                const float t0  = A * G1;
                const float num = cst[j] * t0 + G2 * Bv;
                const float den = Bv * t0;
                const float cn  = num * RCPF(den);
                cst[j] = cn;
                const float e2 = EXP2F(2.f * LOG2E * cn);
                const float h  = (e2 - 1.f) * RCPF((e2 + 1.f) * O);
                wrb[grp * 4 + j][hc] = f2bf(h);
            }
        } else {
            float xvn = 0.f;
            if (t + 2 < Tn) xvn = *xp;
            xp += CIN;
            const short8 ha0 = *(const short8*)&rdb[col][16 + grp * 8];
            const short8 ha1 = *(const short8*)&rdb[col][48 + grp * 8];
            f32x4 cz = bcdv;
            cz = __builtin_amdgcn_mfma_f32_16x16x32_bf16(ha0, wcd[0], cz, 0, 0, 0);
            cz = __builtin_amdgcn_mfma_f32_16x16x32_bf16(ha1, wcd[1], cz, 0, 0, 0);
            if (t + 1 < Tn) wrb[xr][xc] = f2bf(xva);
            xva = xvn;
            if (t > 0) {
                float v = (hw & 1) ? ((hw & 2) ? cz[3] : cz[1])
                                   : ((hw & 2) ? cz[2] : cz[0]);
                float s = (col < 10) ? EXP2F(v * LOG2E) : 0.f;
                s += __int_as_float(__builtin_amdgcn_ds_swizzle(__float_as_int(s), 0x041F));
                s += __int_as_float(__builtin_amdgcn_ds_swizzle(__float_as_int(s), 0x081F));
                s += __int_as_float(__builtin_amdgcn_ds_swizzle(__float_as_int(s), 0x101F));
                s += __int_as_float(__builtin_amdgcn_ds_swizzle(__float_as_int(s), 0x201F));
                const float lse = __logf(s);
                if (col < 10) {
                    lp_p[0] = v - lse;
                } else if (col == 10) {
                    const float d = RCPF(1.f + EXP2F(v));
                    pt_p[0] = d * pnd;
                    pnd *= (1.f - d);
                }
                lp_p += NCLS;
                pt_p += 1;
            }
        }
        __syncthreads();
    }
    if (!gatew) {
        const ushort (*rdb)[104] = comb[Tn & 1];
        const short8 ha0 = *(const short8*)&rdb[col][16 + grp * 8];
        const short8 ha1 = *(const short8*)&rdb[col][48 + grp * 8];
        f32x4 cz = bcdv;
        cz = __builtin_amdgcn_mfma_f32_16x16x32_bf16(ha0, wcd[0], cz, 0, 0, 0);
        cz = __builtin_amdgcn_mfma_f32_16x16x32_bf16(ha1, wcd[1], cz, 0, 0, 0);
        float v = (hw & 1) ? ((hw & 2) ? cz[3] : cz[1])
                           : ((hw & 2) ? cz[2] : cz[0]);
        float s = (col < 10) ? EXP2F(v * LOG2E) : 0.f;
        s += __int_as_float(__builtin_amdgcn_ds_swizzle(__float_as_int(s), 0x041F));
        s += __int_as_float(__builtin_amdgcn_ds_swizzle(__float_as_int(s), 0x081F));
        s += __int_as_float(__builtin_amdgcn_ds_swizzle(__float_as_int(s), 0x101F));
        s += __int_as_float(__builtin_amdgcn_ds_swizzle(__float_as_int(s), 0x201F));
        const float lse = __logf(s);
        if (col < 10)       lp_p[0] = v - lse;
        else if (col == 10) pt_p[0] = pnd;
    }
}

extern "C" void kernel_launch(void* const* d_in, const int* in_sizes, int n_in,
                              void* d_out, int out_size, void* d_ws, size_t ws_size,
                              hipStream_t stream) {
    const float* x  = (const float*)d_in[0];
    const float* Wl = (const float*)d_in[1];
    const float* bl = (const float*)d_in[2];
    const float* Wc = (const float*)d_in[3];
    const float* bc = (const float*)d_in[4];
    const float* Wd = (const float*)d_in[5];
    const float* bd = (const float*)d_in[6];
    float* out = (float*)d_out;

    const size_t logN = (size_t)Bsz * Tn * 12;
    const size_t decN = (size_t)Bsz * Tn;
    const size_t need = (logN + decN) * sizeof(float);

    if (ws_size >= need) {
        float* wslog = (float*)d_ws;
        float* dec   = wslog + logN;
        hipLaunchKernelGGL(rec_kernel, dim3(Bsz / MBR), dim3(256), 0, stream,
                           x, Wl, bl, Wc, bc, Wd, bd, wslog);
        hipLaunchKernelGGL(head_kernel, dim3((Bsz * Tn) / 256), dim3(256), 0, stream,
                           wslog, out, dec);
        hipLaunchKernelGGL(pnd_kernel, dim3(Bsz / 64), dim3(64), 0, stream,
                           dec, out + (size_t)Bsz * Tn * NCLS);
    } else {
        hipLaunchKernelGGL(dualrnn_fused, dim3(Bsz / 16), dim3(512), 0, stream,
                           x, Wl, bl, Wc, bc, Wd, bd, out);
    }
}

// Round 7
// 148.726 us; speedup vs baseline: 1.8022x; 1.8022x over previous
//
#include <hip/hip_runtime.h>
#include <hip/hip_bf16.h>

#define Bsz  4096
#define Tn   256
#define CIN  16
#define NCLS 10
#define MB   16          // full 16-row MFMA tile per block

typedef __attribute__((ext_vector_type(8))) short short8;
typedef __attribute__((ext_vector_type(4))) float f32x4;

#if __has_builtin(__builtin_amdgcn_exp2f)
#define EXP2F(x) __builtin_amdgcn_exp2f(x)
#else
#define EXP2F(x) exp2f(x)
#endif
#define RCPF(x) __builtin_amdgcn_rcpf(x)

#define LOG2E 1.442695041f

// LDS-only barrier: order comb writes/reads across waves WITHOUT draining
// vmcnt (global x loads + output stores stay in flight across steps).
// __syncthreads would emit s_waitcnt vmcnt(0) expcnt(0) lgkmcnt(0) and put
// global store-ack latency on the per-step critical path.
#define BARRIER_LDS() do {                                     \
    asm volatile("s_waitcnt lgkmcnt(0)" ::: "memory");         \
    __builtin_amdgcn_s_barrier();                              \
} while (0)

__device__ inline ushort f2bf(float f) {
    union { float f; unsigned u; } x; x.f = f;
    return (ushort)((x.u + 0x7FFF + ((x.u >> 16) & 1)) >> 16);  // RNE
}

__global__ __launch_bounds__(512, 2) void dualrnn_fused(
    const float* __restrict__ x,  const float* __restrict__ Wl, const float* __restrict__ bl,
    const float* __restrict__ Wc, const float* __restrict__ bc,
    const float* __restrict__ Wd, const float* __restrict__ bd,
    float* __restrict__ out)
{
    // double-buffered: [parity][batch_row][k]; k: 0..15 x, 16..79 h, 80..95 pad(0)
    __shared__ alignas(16) ushort comb[2][16][104];
    const int tid  = threadIdx.x;
    const int wave = tid >> 6;
    const int lane = tid & 63;
    const int col  = lane & 15;
    const int grp  = lane >> 4;
    const int b0   = blockIdx.x * MB;
    const bool gatew = (wave < 4);   // waves 0-3: LSTM gates; waves 4-7: head

    for (int i = tid; i < 2 * 16 * 104; i += 512) ((ushort*)comb)[i] = 0;

    // ---- preload weights (role-specific, loop-invariant in VGPRs) ----
    // gates: fold exp2 scale; sigmoid gates i,f,o: -log2(e); tanh gate g: +2*log2(e).
    // bias folded into the MFMA C-operand (biasv).
    short8 wf[4][3]; f32x4 biasv[4];
    short8 wcd[2];   f32x4 bcdv;
    if (gatew) {
#pragma unroll
        for (int g = 0; g < 4; ++g) {
            const float sc = (g == 3) ? 2.f * LOG2E : -LOG2E;
            const int R = g * 64 + wave * 16 + col;
            const float bv = bl[R] * sc;
            biasv[g] = (f32x4){bv, bv, bv, bv};
#pragma unroll
            for (int kt = 0; kt < 3; ++kt)
#pragma unroll
                for (int i = 0; i < 8; ++i) {
                    const int k = kt * 32 + grp * 8 + i;
                    wf[g][kt][i] = (short)f2bf(k < 80 ? Wl[R * 80 + k] * sc : 0.f);
                }
        }
    } else {
        // class lanes (col<10): natural scale. dec lane (col==10): fold -log2(e).
#pragma unroll
        for (int kt = 0; kt < 2; ++kt)
#pragma unroll
            for (int i = 0; i < 8; ++i) {
                const int k = kt * 32 + grp * 8 + i;
                float v = 0.f;
                if (col < 10)       v = Wc[col * 64 + k];
                else if (col == 10) v = Wd[k] * -LOG2E;
                wcd[kt][i] = (short)f2bf(v);
            }
        const float bv = (col < 10) ? bc[col] : ((col == 10) ? bd[0] * -LOG2E : 0.f);
        bcdv = (f32x4){bv, bv, bv, bv};
    }

    __syncthreads();   // zeroing done before x_0 write (avoid zero/x race)

    if (tid < 256) {   // x_0 into comb[0]; h-section stays zero
        const int r = tid >> 4, ch = tid & 15;
        comb[0][r][ch] = f2bf(x[((size_t)(b0 + r) * Tn) * CIN + ch]);
    }
    __syncthreads();

    float cst[4] = {0, 0, 0, 0};   // c state (gate waves), rows grp*4+j, unit 16*wave+col
    float pnd = 1.f;               // head waves, lanes col==10, row grp*4+hw

    const int hw  = wave & 3;            // head-wave id 0..3
    const int row = grp * 4 + hw;        // output row this head thread owns (slot j==hw)
    float* lp_p = out + ((size_t)(b0 + row) * Tn) * NCLS + col;              // [B][T][10]
    float* pt_p = out + (size_t)Bsz * Tn * NCLS + (size_t)(b0 + row) * Tn;   // [B][T]
    const int t2 = hw * 64 + lane;       // 0..255 across head waves
    const int xr = t2 >> 4, xc = t2 & 15;
    // 2-deep x prefetch: xva holds x_{t+1} (written this iter); load x_{t+2} now.
    float xva = 0.f;
    const float* xp = x + ((size_t)(b0 + xr) * Tn + 2) * CIN + xc;
    if (!gatew) xva = x[((size_t)(b0 + xr) * Tn + 1) * CIN + xc];

    // iter t: read comb[t&1] = {x_t, h_{t-1}}; gates write h_t, head writes x_{t+1}
    // into comb[(t+1)&1]; head outputs step t-1 from h_{t-1}. One LDS-barrier/iter.
    for (int t = 0; t < Tn; ++t) {
        const ushort (*rdb)[104] = comb[t & 1];
        ushort (*wrb)[104] = comb[(t + 1) & 1];
        if (gatew) {
            const short8 a0 = *(const short8*)&rdb[col][ 0 + grp * 8];
            const short8 a1 = *(const short8*)&rdb[col][32 + grp * 8];
            const short8 a2 = *(const short8*)&rdb[col][64 + grp * 8];
            f32x4 acc[4];
#pragma unroll
            for (int g = 0; g < 4; ++g) {
                f32x4 z = biasv[g];
                z = __builtin_amdgcn_mfma_f32_16x16x32_bf16(a0, wf[g][0], z, 0, 0, 0);
                z = __builtin_amdgcn_mfma_f32_16x16x32_bf16(a1, wf[g][1], z, 0, 0, 0);
                z = __builtin_amdgcn_mfma_f32_16x16x32_bf16(a2, wf[g][2], z, 0, 0, 0);
                acc[g] = z;
            }
            const int hc = 16 + wave * 16 + col;
#pragma unroll
            for (int j = 0; j < 4; ++j) {
                // gi=1/A, gf=1/B, tanh_g=G2/G1, go=1/O
                const float ei = EXP2F(acc[0][j]);
                const float ef = EXP2F(acc[1][j]);
                const float eo = EXP2F(acc[2][j]);
                const float eg = EXP2F(acc[3][j]);
                const float A  = 1.f + ei, Bv = 1.f + ef;
                const float G1 = eg + 1.f, G2 = eg - 1.f, O = 1.f + eo;
                const float t0  = A * G1;
                const float num = cst[j] * t0 + G2 * Bv;
                const float den = Bv * t0;
                const float cn  = num * RCPF(den);
                cst[j] = cn;
                const float e2 = EXP2F(2.f * LOG2E * cn);
                const float h  = (e2 - 1.f) * RCPF((e2 + 1.f) * O);
                wrb[grp * 4 + j][hc] = f2bf(h);
            }
        } else {
            // issue x_{t+2} load first (covered by this whole step)
            float xvn = 0.f;
            if (t + 2 < Tn) xvn = *xp;
            xp += CIN;
            const short8 ha0 = *(const short8*)&rdb[col][16 + grp * 8];
            const short8 ha1 = *(const short8*)&rdb[col][48 + grp * 8];
            f32x4 cz = bcdv;
            cz = __builtin_amdgcn_mfma_f32_16x16x32_bf16(ha0, wcd[0], cz, 0, 0, 0);
            cz = __builtin_amdgcn_mfma_f32_16x16x32_bf16(ha1, wcd[1], cz, 0, 0, 0);
            if (t + 1 < Tn) wrb[xr][xc] = f2bf(xva);   // x_{t+1}, loaded LAST iter
            xva = xvn;
            if (t > 0) {
                float v = (hw & 1) ? ((hw & 2) ? cz[3] : cz[1])
                                   : ((hw & 2) ? cz[2] : cz[0]);
                // |logits| small -> skip max-subtraction; sum exp over 16-lane group
                float s = (col < 10) ? EXP2F(v * LOG2E) : 0.f;
                s += __int_as_float(__builtin_amdgcn_ds_swizzle(__float_as_int(s), 0x041F));
                s += __int_as_float(__builtin_amdgcn_ds_swizzle(__float_as_int(s), 0x081F));
                s += __int_as_float(__builtin_amdgcn_ds_swizzle(__float_as_int(s), 0x101F));
                s += __int_as_float(__builtin_amdgcn_ds_swizzle(__float_as_int(s), 0x201F));
                const float lse = __logf(s);
                if (col < 10) {
                    lp_p[0] = v - lse;
                } else if (col == 10) {
                    const float d = RCPF(1.f + EXP2F(v));   // -log2e folded in wcd
                    pt_p[0] = d * pnd;
                    pnd *= (1.f - d);
                }
                lp_p += NCLS;
                pt_p += 1;
            }
        }
        BARRIER_LDS();
    }

    // epilogue: output step Tn-1 from h_{Tn-1} in comb[Tn&1]
    if (!gatew) {
        const ushort (*rdb)[104] = comb[Tn & 1];
        const short8 ha0 = *(const short8*)&rdb[col][16 + grp * 8];
        const short8 ha1 = *(const short8*)&rdb[col][48 + grp * 8];
        f32x4 cz = bcdv;
        cz = __builtin_amdgcn_mfma_f32_16x16x32_bf16(ha0, wcd[0], cz, 0, 0, 0);
        cz = __builtin_amdgcn_mfma_f32_16x16x32_bf16(ha1, wcd[1], cz, 0, 0, 0);
        float v = (hw & 1) ? ((hw & 2) ? cz[3] : cz[1])
                           : ((hw & 2) ? cz[2] : cz[0]);
        float s = (col < 10) ? EXP2F(v * LOG2E) : 0.f;
        s += __int_as_float(__builtin_amdgcn_ds_swizzle(__float_as_int(s), 0x041F));
        s += __int_as_float(__builtin_amdgcn_ds_swizzle(__float_as_int(s), 0x081F));
        s += __int_as_float(__builtin_amdgcn_ds_swizzle(__float_as_int(s), 0x101F));
        s += __int_as_float(__builtin_amdgcn_ds_swizzle(__float_as_int(s), 0x201F));
        const float lse = __logf(s);
        if (col < 10)       lp_p[0] = v - lse;
        else if (col == 10) pt_p[0] = pnd;   // is_last: Pt = pnd_{T-1}
    }
}

extern "C" void kernel_launch(void* const* d_in, const int* in_sizes, int n_in,
                              void* d_out, int out_size, void* d_ws, size_t ws_size,
                              hipStream_t stream) {
    const float* x  = (const float*)d_in[0];
    const float* Wl = (const float*)d_in[1];
    const float* bl = (const float*)d_in[2];
    const float* Wc = (const float*)d_in[3];
    const float* bc = (const float*)d_in[4];
    const float* Wd = (const float*)d_in[5];
    const float* bd = (const float*)d_in[6];
    float* out = (float*)d_out;

    hipLaunchKernelGGL(dualrnn_fused, dim3(Bsz / MB), dim3(512), 0, stream,
                       x, Wl, bl, Wc, bc, Wd, bd, out);
}